// Round 2
// baseline (445.310 us; speedup 1.0000x reference)
//
#include <hip/hip_runtime.h>
#include <cstdint>
#include <cstddef>

// ---------------------------------------------------------------------------
// SpaceSelfAttentionModality on MI355X (gfx950)
// cvt(x) -> transpose-cvt(W) -> QKV GEMM (writes q,k row-major + V TRANSPOSED)
//   -> flash attn (128 q-rows/block, double-buffered K/V^T staging, tile skip)
//   -> output-proj GEMM -> f32 out.
// ---------------------------------------------------------------------------

#define BT_N    8
#define SEQ_N   1024
#define DMODEL  1024
#define NHEADS  16
#define HDIM    64
#define NLAT    64

typedef __attribute__((ext_vector_type(4))) float f32x4;
typedef __attribute__((ext_vector_type(8))) __bf16 bf16x8;
typedef __attribute__((ext_vector_type(4))) short short4v;
typedef __attribute__((ext_vector_type(8))) short short8v;

__device__ __forceinline__ short f2bf(float f) {
  union { float f; unsigned u; } x; x.f = f;
  unsigned r = x.u + 0x7fffu + ((x.u >> 16) & 1u);   // RNE (no NaN inputs here)
  return (short)(r >> 16);
}

#define GLOAD_LDS16(gsrc, ldst)                                                   \
  __builtin_amdgcn_global_load_lds(                                               \
      (const __attribute__((address_space(1))) void*)(gsrc),                      \
      (__attribute__((address_space(3))) void*)(ldst), 16, 0, 0)

#define MFMA16(a, b, c) __builtin_amdgcn_mfma_f32_16x16x32_bf16((a), (b), (c), 0, 0, 0)

// ---------------------------------------------------------------------------
// Kernel 1: plain f32 -> bf16 convert (vectorized float4 -> 4x bf16)
// ---------------------------------------------------------------------------
__global__ __launch_bounds__(256)
void cvt_plain(const float* __restrict__ in, short* __restrict__ out, int n4) {
  int i = blockIdx.x * 256 + threadIdx.x;
  if (i >= n4) return;
  float4 f = reinterpret_cast<const float4*>(in)[i];
  short4v o;
  o.x = f2bf(f.x); o.y = f2bf(f.y); o.z = f2bf(f.z); o.w = f2bf(f.w);
  reinterpret_cast<short4v*>(out)[i] = o;
}

// ---------------------------------------------------------------------------
// Kernel 2: 1024x1024 f32 -> transposed bf16 (out[c][r] = in[r][c])
// ---------------------------------------------------------------------------
__global__ __launch_bounds__(256)
void cvt_T(const float* __restrict__ in, short* __restrict__ out) {
  __shared__ short t[64][65];
  int tc = blockIdx.x * 64, tr = blockIdx.y * 64;
  int lx = threadIdx.x & 63, ly = threadIdx.x >> 6;  // ly in 0..3
#pragma unroll
  for (int i = 0; i < 16; ++i) {
    int r = ly + i * 4;
    t[r][lx] = f2bf(in[(size_t)(tr + r) * 1024 + tc + lx]);
  }
  __syncthreads();
#pragma unroll
  for (int i = 0; i < 16; ++i) {
    int c = ly + i * 4;
    out[(size_t)(tc + c) * 1024 + tr + lx] = t[lx][c];
  }
}

// ---------------------------------------------------------------------------
// Kernel 3/5: bf16 GEMM, C = A[M x 1024] * Bt[N x 1024]^T.
// 128x128 tile, BK=64, 4 waves, double-buffered global_load_lds staging.
// MODE 0: QKV epilogue (bias, q-scale; q,k -> [bt][h][s][d]; v -> [bt][h][d][s]).
// MODE 1: proj epilogue (add bo, f32 row-major out).
// ---------------------------------------------------------------------------
template <int MODE>
__global__ __launch_bounds__(256, 2)
void gemm_bf16(const short* __restrict__ A, const short* __restrict__ Bt,
               const float* __restrict__ bq, const float* __restrict__ bk,
               const float* __restrict__ bv, short* __restrict__ qkv_out,
               const float* __restrict__ bo, float* __restrict__ out) {
  __shared__ __align__(16) short sA[2][128 * 64];
  __shared__ __align__(16) short sB[2][128 * 64];
  const int tid = threadIdx.x;
  const int l = tid & 63, w = tid >> 6;
  const int wr = w >> 1, wc = w & 1;
  const int lg = l >> 4, li = l & 15;
  const int m0 = blockIdx.y * 128, n0 = blockIdx.x * 128;

  f32x4 acc[4][4] = {};

  auto stage = [&](int buf, int kt) {
    const int kb = kt * 64;
#pragma unroll
    for (int i = 0; i < 4; ++i) {
      int ch = tid + 256 * i;        // 0..1023, 16B chunks
      int r = ch >> 3, c = ch & 7;
      GLOAD_LDS16(A + (size_t)(m0 + r) * 1024 + kb + c * 8, &sA[buf][ch * 8]);
    }
#pragma unroll
    for (int i = 0; i < 4; ++i) {
      int ch = tid + 256 * i;
      int r = ch >> 3, c = ch & 7;
      GLOAD_LDS16(Bt + (size_t)(n0 + r) * 1024 + kb + c * 8, &sB[buf][ch * 8]);
    }
  };

  stage(0, 0);
  __syncthreads();
  const int NK = 1024 / 64;
  for (int kt = 0; kt < NK; ++kt) {
    const int cur = kt & 1;
    if (kt + 1 < NK) stage(cur ^ 1, kt + 1);
#pragma unroll
    for (int kk = 0; kk < 64; kk += 32) {
      bf16x8 af[4], bfr[4];
#pragma unroll
      for (int mi = 0; mi < 4; ++mi)
        af[mi] = *(const bf16x8*)&sA[cur][(wr * 64 + mi * 16 + li) * 64 + kk + lg * 8];
#pragma unroll
      for (int ni = 0; ni < 4; ++ni)
        bfr[ni] = *(const bf16x8*)&sB[cur][(wc * 64 + ni * 16 + li) * 64 + kk + lg * 8];
#pragma unroll
      for (int mi = 0; mi < 4; ++mi)
#pragma unroll
        for (int ni = 0; ni < 4; ++ni)
          acc[mi][ni] = MFMA16(af[mi], bfr[ni], acc[mi][ni]);
    }
    __syncthreads();
  }

  // Epilogue. C/D layout: col = lane&15, row = (lane>>4)*4 + reg  [m89-verified]
  if (MODE == 0) {
#pragma unroll
    for (int ni = 0; ni < 4; ++ni) {
      const int n = n0 + wc * 64 + ni * 16 + li;  // 0..3071 (which is wave-uniform)
      const int which = n >> 10;                  // 0=q 1=k 2=v
      const int hd_idx = n & 1023;
      const float* bias = (which == 0) ? bq : ((which == 1) ? bk : bv);
      const float bval = bias[hd_idx];
      const int h = hd_idx >> 6, d = hd_idx & 63;
      short* dst = qkv_out + (size_t)which * (BT_N * NHEADS * SEQ_N * HDIM);
#pragma unroll
      for (int mi = 0; mi < 4; ++mi) {
        const int mbase = m0 + wr * 64 + mi * 16 + lg * 4;
        const int bt = mbase >> 10, s0 = mbase & 1023;   // 4 regs never cross bt
        if (which == 2) {
          // V transposed: [bt][h][d][s], 4 consecutive s -> one 8B store
          short4v pv;
#pragma unroll
          for (int reg = 0; reg < 4; ++reg) pv[reg] = f2bf(acc[mi][ni][reg] + bval);
          *(short4v*)(dst + (((size_t)(bt * NHEADS + h)) * HDIM + d) * SEQ_N + s0) = pv;
        } else {
#pragma unroll
          for (int reg = 0; reg < 4; ++reg) {
            float v = acc[mi][ni][reg] + bval;
            if (which == 0) v *= 0.125f;          // 1/sqrt(64)
            dst[(((size_t)(bt * NHEADS + h)) * SEQ_N + s0 + reg) * HDIM + d] = f2bf(v);
          }
        }
      }
    }
  } else {
#pragma unroll
    for (int ni = 0; ni < 4; ++ni) {
      const int n = n0 + wc * 64 + ni * 16 + li;
      const float bval = bo[n];
#pragma unroll
      for (int mi = 0; mi < 4; ++mi) {
#pragma unroll
        for (int reg = 0; reg < 4; ++reg) {
          const int m = m0 + wr * 64 + mi * 16 + lg * 4 + reg;
          out[(size_t)m * 1024 + n] = acc[mi][ni][reg] + bval;
        }
      }
    }
  }
}

// ---------------------------------------------------------------------------
// Kernel 4: flash attention, 128 q-rows/block (8 waves), KBLK=64,
// double-buffered K/V^T via global_load_lds (pre-swizzled source),
// generic tile classification: skip / full (no mask) / mixed (element mask).
// One __syncthreads() per tile-step.
// ---------------------------------------------------------------------------
__global__ __launch_bounds__(512, 6)
void attn_kernel(const short* __restrict__ qg, const short* __restrict__ kg,
                 const short* __restrict__ vtg, const int* __restrict__ ids,
                 short* __restrict__ ao) {
  __shared__ __align__(16) short sK[2][64 * 64];
  __shared__ __align__(16) short sVT[2][64 * 64];   // V^T tile: [d][s], swizzled
  __shared__ __align__(16) short sP[8][16 * 64];    // per-wave P, swizzled
  __shared__ int sid[SEQ_N];
  __shared__ int anyF[16], allF[16];
  __shared__ int tlist[16], tmix[16], ntile;

  const int tid = threadIdx.x;
  const int l = tid & 63, w = tid >> 6;
  const int lg = l >> 4, li = l & 15;
  const int qb = blockIdx.x * 128;
  const int h = blockIdx.y, bt = blockIdx.z;
  const size_t hb = ((size_t)(bt * NHEADS + h)) * SEQ_N * HDIM;  // q,k,vT same stride

  for (int i = tid; i < SEQ_N; i += 512) sid[i] = ids[i];
  if (tid < 16) { anyF[tid] = 0; allF[tid] = 1; }
  __syncthreads();
  {
    // 32 threads per tile t; thread checks 2 s-values vs all 128 q rows
    const int t = tid >> 5, j = tid & 31;
    int any = 0, all = 1;
#pragma unroll
    for (int ss = 0; ss < 2; ++ss) {
      const int sv = sid[t * 64 + j * 2 + ss];
      for (int r = 0; r < 128; ++r) {
        const int a = (qb + r < NLAT) || (sid[qb + r] == sv);
        any |= a; all &= a;
      }
    }
    if (any) atomicOr(&anyF[t], 1);
    if (!all) atomicAnd(&allF[t], 0);
  }
  __syncthreads();
  if (tid == 0) {
    int n = 0;
    for (int t = 0; t < 16; ++t)
      if (anyF[t]) { tlist[n] = t; tmix[n] = !allF[t]; ++n; }
    ntile = n;
  }
  __syncthreads();
  const int nt = ntile;

  // Q fragments: wave w owns rows qb + 16w .. +16 (q pre-scaled by 1/8)
  const int qrow = qb + w * 16;
  const bf16x8 qf0 = *(const bf16x8*)(qg + hb + (size_t)(qrow + li) * HDIM + lg * 8);
  const bf16x8 qf1 = *(const bf16x8*)(qg + hb + (size_t)(qrow + li) * HDIM + 32 + lg * 8);
  int qid[4]; bool lat[4]; float mrun[4], lrun[4];
#pragma unroll
  for (int reg = 0; reg < 4; ++reg) {
    const int qr = qrow + lg * 4 + reg;
    qid[reg] = sid[qr];
    lat[reg] = (qr < NLAT);
    mrun[reg] = -1e30f;
    lrun[reg] = 0.f;
  }
  f32x4 oacc[4] = {};

  // stage one 64-s tile: 512 threads x 1 chunk each per array, swizzled source
  auto stage = [&](int buf, int t) {
    const int kb = t * 64;
    const int r = tid >> 3, c = tid & 7;
    const int cs = (c ^ (r & 7)) * 8;
    GLOAD_LDS16(kg + hb + (size_t)(kb + r) * HDIM + cs, &sK[buf][tid * 8]);
    GLOAD_LDS16(vtg + hb + (size_t)r * SEQ_N + kb + cs, &sVT[buf][tid * 8]);
  };

  if (nt > 0) stage(0, tlist[0]);
  __syncthreads();                                   // drains vmcnt

  for (int i = 0; i < nt; ++i) {
    const int b = i & 1;
    if (i + 1 < nt) stage(b ^ 1, tlist[i + 1]);      // overlapped with compute
    const int kb = tlist[i] * 64;

    // QK^T: S[16q x 64s] in 4 s-tiles
    f32x4 sc[4];
#pragma unroll
    for (int st = 0; st < 4; ++st) {
      const int srow = st * 16 + li;
      const bf16x8 kf0 = *(const bf16x8*)&sK[b][srow * 64 + ((lg ^ (srow & 7)) * 8)];
      const bf16x8 kf1 = *(const bf16x8*)&sK[b][srow * 64 + (((lg + 4) ^ (srow & 7)) * 8)];
      f32x4 z = {0.f, 0.f, 0.f, 0.f};
      z = MFMA16(qf0, kf0, z);
      z = MFMA16(qf1, kf1, z);
      sc[st] = z;
    }
    if (tmix[i]) {                                   // element mask only if mixed
#pragma unroll
      for (int st = 0; st < 4; ++st) {
        const int sv = sid[kb + st * 16 + li];
#pragma unroll
        for (int reg = 0; reg < 4; ++reg)
          if (!(lat[reg] || (qid[reg] == sv))) sc[st][reg] = -1e30f;
      }
    }
    // online softmax (row lives across 16 lanes of a group)
    float ps[4];
#pragma unroll
    for (int reg = 0; reg < 4; ++reg) {
      float mx = fmaxf(fmaxf(sc[0][reg], sc[1][reg]), fmaxf(sc[2][reg], sc[3][reg]));
      mx = fmaxf(mx, __shfl_xor(mx, 1, 64));
      mx = fmaxf(mx, __shfl_xor(mx, 2, 64));
      mx = fmaxf(mx, __shfl_xor(mx, 4, 64));
      mx = fmaxf(mx, __shfl_xor(mx, 8, 64));
      const float mn = fmaxf(mrun[reg], mx);
      const float scale = __expf(mrun[reg] - mn);
      mrun[reg] = mn;
      lrun[reg] *= scale;
#pragma unroll
      for (int dt = 0; dt < 4; ++dt) oacc[dt][reg] *= scale;
      ps[reg] = 0.f;
    }
#pragma unroll
    for (int st = 0; st < 4; ++st) {
#pragma unroll
      for (int reg = 0; reg < 4; ++reg) {
        const float p = __expf(sc[st][reg] - mrun[reg]);
        ps[reg] += p;
        const int row = lg * 4 + reg, scol = st * 16 + li;
        sP[w][row * 64 + (((scol >> 3) ^ (row & 7)) * 8) + (scol & 7)] = f2bf(p);
      }
    }
#pragma unroll
    for (int reg = 0; reg < 4; ++reg) {
      float s4 = ps[reg];
      s4 += __shfl_xor(s4, 1, 64);
      s4 += __shfl_xor(s4, 2, 64);
      s4 += __shfl_xor(s4, 4, 64);
      s4 += __shfl_xor(s4, 8, 64);
      lrun[reg] += s4;
    }
    // sP is per-wave: compiler-inserted lgkmcnt orders write->read, no barrier.

    // PV: out[16q x 64d] += P[16q x 64s] * V^T[64d x 64s]^T
#pragma unroll
    for (int half = 0; half < 2; ++half) {
      const bf16x8 pa = *(const bf16x8*)&sP[w][li * 64 + (((lg + 4 * half) ^ (li & 7)) * 8)];
#pragma unroll
      for (int dt = 0; dt < 4; ++dt) {
        const int d = dt * 16 + li;
        const bf16x8 vb = *(const bf16x8*)&sVT[b][d * 64 + (((lg + 4 * half) ^ (d & 7)) * 8)];
        oacc[dt] = MFMA16(pa, vb, oacc[dt]);
      }
    }
    __syncthreads();   // one barrier/tile: drains stage vmcnt, protects buffers
  }

  // epilogue: divide by denom, write [bt*S + s][h*64 + d] bf16
#pragma unroll
  for (int dt = 0; dt < 4; ++dt) {
#pragma unroll
    for (int reg = 0; reg < 4; ++reg) {
      const int row = qrow + lg * 4 + reg;
      const int d = dt * 16 + li;
      const float o = oacc[dt][reg] / lrun[reg];
      ao[((size_t)(bt * SEQ_N + row)) * DMODEL + h * HDIM + d] = f2bf(o);
    }
  }
}

// ---------------------------------------------------------------------------
// Host launcher
// ---------------------------------------------------------------------------
extern "C" void kernel_launch(void* const* d_in, const int* in_sizes, int n_in,
                              void* d_out, int out_size, void* d_ws, size_t ws_size,
                              hipStream_t stream) {
  const float* x  = (const float*)d_in[0];
  const int* ids  = (const int*)d_in[1];
  const float* Wq = (const float*)d_in[2];
  const float* bq = (const float*)d_in[3];
  const float* Wk = (const float*)d_in[4];
  const float* bk = (const float*)d_in[5];
  const float* Wv = (const float*)d_in[6];
  const float* bv = (const float*)d_in[7];
  const float* Wo = (const float*)d_in[8];
  const float* bo = (const float*)d_in[9];
  float* out = (float*)d_out;

  short* ws     = (short*)d_ws;
  short* x_bf   = ws;                          // 8192*1024
  short* wqkv_t = x_bf + 8388608;              // 3072*1024 (B^T: [n][k])
  short* wo_t   = wqkv_t + 3145728;            // 1024*1024 (B^T: [o][k])
  short* q_bf   = wo_t + 1048576;              // [bt][h][s][d]
  short* k_bf   = q_bf + 8388608;              // [bt][h][s][d]
  short* vt_bf  = k_bf + 8388608;              // [bt][h][d][s]  (transposed!)
  short* ao_bf  = vt_bf + 8388608;             // [bt*s][h*d]

  cvt_plain<<<8192, 256, 0, stream>>>(x, x_bf, 2097152);
  dim3 tg(16, 16);
  cvt_T<<<tg, 256, 0, stream>>>(Wq, wqkv_t);
  cvt_T<<<tg, 256, 0, stream>>>(Wk, wqkv_t + 1048576);
  cvt_T<<<tg, 256, 0, stream>>>(Wv, wqkv_t + 2097152);
  cvt_T<<<tg, 256, 0, stream>>>(Wo, wo_t);

  gemm_bf16<0><<<dim3(24, 64), 256, 0, stream>>>(x_bf, wqkv_t, bq, bk, bv,
                                                 q_bf, nullptr, nullptr);
  attn_kernel<<<dim3(8, NHEADS, BT_N), 512, 0, stream>>>(q_bf, k_bf, vt_bf, ids, ao_bf);
  gemm_bf16<1><<<dim3(8, 64), 256, 0, stream>>>(ao_bf, wo_t, nullptr, nullptr, nullptr,
                                                nullptr, bo, out);
}

// Round 4
// 321.577 us; speedup vs baseline: 1.3848x; 1.3848x over previous
//
#include <hip/hip_runtime.h>
#include <cstdint>
#include <cstddef>

// ---------------------------------------------------------------------------
// SpaceSelfAttentionModality on MI355X (gfx950)
// cvt(x) -> transpose-cvt(W) -> QKV GEMM (q,k row-major + V TRANSPOSED)
//   -> flash attn (swapped-QK^T 32x32 MFMA, in-register softmax, tile skip)
//   -> output-proj GEMM -> f32 out.
// ---------------------------------------------------------------------------

#define BT_N    8
#define SEQ_N   1024
#define DMODEL  1024
#define NHEADS  16
#define HDIM    64
#define NLAT    64

typedef __attribute__((ext_vector_type(4))) float f32x4;
typedef __attribute__((ext_vector_type(16))) float f32x16;
typedef __attribute__((ext_vector_type(8))) __bf16 bf16x8;
typedef __attribute__((ext_vector_type(4))) short short4v;
typedef __attribute__((ext_vector_type(8))) short short8v;
typedef __attribute__((ext_vector_type(4))) int int4v;
typedef __attribute__((ext_vector_type(2))) unsigned int uint2v;

__device__ __forceinline__ short f2bf(float f) {
  union { float f; unsigned u; } x; x.f = f;
  unsigned r = x.u + 0x7fffu + ((x.u >> 16) & 1u);   // RNE (no NaN inputs here)
  return (short)(r >> 16);
}

// swap hi-half of a with lo-half of b (lane pairs l <-> l^32)
__device__ __forceinline__ void plswap(int& a, int& b) {
#if __has_builtin(__builtin_amdgcn_permlane32_swap)
  uint2v r = __builtin_amdgcn_permlane32_swap((unsigned)a, (unsigned)b, false, false);
  a = (int)r.x; b = (int)r.y;
#else
  asm volatile("v_permlane32_swap_b32 %0, %1" : "+v"(a), "+v"(b));
#endif
}

#define GLOAD_LDS16(gsrc, ldst)                                                   \
  __builtin_amdgcn_global_load_lds(                                               \
      (const __attribute__((address_space(1))) void*)(gsrc),                      \
      (__attribute__((address_space(3))) void*)(ldst), 16, 0, 0)

#define MFMA16(a, b, c) __builtin_amdgcn_mfma_f32_16x16x32_bf16((a), (b), (c), 0, 0, 0)
#define MFMA32(a, b, c) __builtin_amdgcn_mfma_f32_32x32x16_bf16((a), (b), (c), 0, 0, 0)

// 1/sqrt(64) * log2(e): scores come out in log2 domain -> softmax uses exp2
#define QSCALE 0.18033688011112f

// ---------------------------------------------------------------------------
// Kernel 1: plain f32 -> bf16 convert
// ---------------------------------------------------------------------------
__global__ __launch_bounds__(256)
void cvt_plain(const float* __restrict__ in, short* __restrict__ out, int n4) {
  int i = blockIdx.x * 256 + threadIdx.x;
  if (i >= n4) return;
  float4 f = reinterpret_cast<const float4*>(in)[i];
  short4v o;
  o.x = f2bf(f.x); o.y = f2bf(f.y); o.z = f2bf(f.z); o.w = f2bf(f.w);
  reinterpret_cast<short4v*>(out)[i] = o;
}

// ---------------------------------------------------------------------------
// Kernel 2: 1024x1024 f32 -> transposed bf16 (out[c][r] = in[r][c])
// ---------------------------------------------------------------------------
__global__ __launch_bounds__(256)
void cvt_T(const float* __restrict__ in, short* __restrict__ out) {
  __shared__ short t[64][65];
  int tc = blockIdx.x * 64, tr = blockIdx.y * 64;
  int lx = threadIdx.x & 63, ly = threadIdx.x >> 6;
#pragma unroll
  for (int i = 0; i < 16; ++i) {
    int r = ly + i * 4;
    t[r][lx] = f2bf(in[(size_t)(tr + r) * 1024 + tc + lx]);
  }
  __syncthreads();
#pragma unroll
  for (int i = 0; i < 16; ++i) {
    int c = ly + i * 4;
    out[(size_t)(tc + c) * 1024 + tr + lx] = t[lx][c];
  }
}

// ---------------------------------------------------------------------------
// Kernel 3/5: bf16 GEMM, C = A[M x 1024] * Bt[N x 1024]^T. (m97 structure)
// MODE 0: QKV epilogue (bias, q log2e-scale; q,k -> [bt][h][s][d]; v -> [bt][h][d][s]).
// MODE 1: proj epilogue (add bo, f32 row-major out).
// ---------------------------------------------------------------------------
template <int MODE>
__global__ __launch_bounds__(256, 2)
void gemm_bf16(const short* __restrict__ A, const short* __restrict__ Bt,
               const float* __restrict__ bq, const float* __restrict__ bk,
               const float* __restrict__ bv, short* __restrict__ qkv_out,
               const float* __restrict__ bo, float* __restrict__ out) {
  __shared__ __align__(16) short sA[2][128 * 64];
  __shared__ __align__(16) short sB[2][128 * 64];
  const int tid = threadIdx.x;
  const int l = tid & 63, w = tid >> 6;
  const int wr = w >> 1, wc = w & 1;
  const int lg = l >> 4, li = l & 15;
  const int m0 = blockIdx.y * 128, n0 = blockIdx.x * 128;

  f32x4 acc[4][4] = {};

  auto stage = [&](int buf, int kt) {
    const int kb = kt * 64;
#pragma unroll
    for (int i = 0; i < 4; ++i) {
      int ch = tid + 256 * i;
      int r = ch >> 3, c = ch & 7;
      GLOAD_LDS16(A + (size_t)(m0 + r) * 1024 + kb + c * 8, &sA[buf][ch * 8]);
    }
#pragma unroll
    for (int i = 0; i < 4; ++i) {
      int ch = tid + 256 * i;
      int r = ch >> 3, c = ch & 7;
      GLOAD_LDS16(Bt + (size_t)(n0 + r) * 1024 + kb + c * 8, &sB[buf][ch * 8]);
    }
  };

  stage(0, 0);
  __syncthreads();
  const int NK = 1024 / 64;
  for (int kt = 0; kt < NK; ++kt) {
    const int cur = kt & 1;
    if (kt + 1 < NK) stage(cur ^ 1, kt + 1);
#pragma unroll
    for (int kk = 0; kk < 64; kk += 32) {
      bf16x8 af[4], bfr[4];
#pragma unroll
      for (int mi = 0; mi < 4; ++mi)
        af[mi] = *(const bf16x8*)&sA[cur][(wr * 64 + mi * 16 + li) * 64 + kk + lg * 8];
#pragma unroll
      for (int ni = 0; ni < 4; ++ni)
        bfr[ni] = *(const bf16x8*)&sB[cur][(wc * 64 + ni * 16 + li) * 64 + kk + lg * 8];
#pragma unroll
      for (int mi = 0; mi < 4; ++mi)
#pragma unroll
        for (int ni = 0; ni < 4; ++ni)
          acc[mi][ni] = MFMA16(af[mi], bfr[ni], acc[mi][ni]);
    }
    __syncthreads();
  }

  if (MODE == 0) {
#pragma unroll
    for (int ni = 0; ni < 4; ++ni) {
      const int n = n0 + wc * 64 + ni * 16 + li;
      const int which = n >> 10;                  // 0=q 1=k 2=v
      const int hd_idx = n & 1023;
      const float* bias = (which == 0) ? bq : ((which == 1) ? bk : bv);
      const float bval = bias[hd_idx];
      const int h = hd_idx >> 6, d = hd_idx & 63;
      short* dst = qkv_out + (size_t)which * (BT_N * NHEADS * SEQ_N * HDIM);
#pragma unroll
      for (int mi = 0; mi < 4; ++mi) {
        const int mbase = m0 + wr * 64 + mi * 16 + lg * 4;
        const int bt = mbase >> 10, s0 = mbase & 1023;
        if (which == 2) {
          short4v pv;
#pragma unroll
          for (int reg = 0; reg < 4; ++reg) pv[reg] = f2bf(acc[mi][ni][reg] + bval);
          *(short4v*)(dst + (((size_t)(bt * NHEADS + h)) * HDIM + d) * SEQ_N + s0) = pv;
        } else {
#pragma unroll
          for (int reg = 0; reg < 4; ++reg) {
            float v = acc[mi][ni][reg] + bval;
            if (which == 0) v *= QSCALE;
            dst[(((size_t)(bt * NHEADS + h)) * SEQ_N + s0 + reg) * HDIM + d] = f2bf(v);
          }
        }
      }
    }
  } else {
#pragma unroll
    for (int ni = 0; ni < 4; ++ni) {
      const int n = n0 + wc * 64 + ni * 16 + li;
      const float bval = bo[n];
#pragma unroll
      for (int mi = 0; mi < 4; ++mi) {
#pragma unroll
        for (int reg = 0; reg < 4; ++reg) {
          const int m = m0 + wr * 64 + mi * 16 + lg * 4 + reg;
          out[(size_t)m * 1024 + n] = acc[mi][ni][reg] + bval;
        }
      }
    }
  }
}

// ---------------------------------------------------------------------------
// Kernel 4: flash attention, swapped-QK^T structure (m214/§B port):
//   4 waves x 32 q-rows = 128 q/block; KVBLK=64; mfma_32x32x16.
//   QK^T computed as mfma(A=K, B=Q) -> D = P[s][q]: lane owns one q column,
//   softmax is IN-LANE (31 fmax + permlane32_swap pair-combine, no shfl/LDS).
//   P -> bf16 PV A-fragments via cvt_pk_bf16 + permlane32_swap (T12).
//   O accumulates as D[d][q]; per-lane scalar rescale; exp2 domain.
// ---------------------------------------------------------------------------
__global__ __launch_bounds__(256, 4)
void attn_kernel(const short* __restrict__ qg, const short* __restrict__ kg,
                 const short* __restrict__ vtg, const int* __restrict__ ids,
                 short* __restrict__ ao) {
  __shared__ __align__(16) short sK[2][64 * 64];    // K tile [s][d], chunk-swizzled
  __shared__ __align__(16) short sVT[2][64 * 64];   // V^T tile [d][s], chunk-swizzled
  __shared__ int sid[SEQ_N];
  __shared__ int tmin16[16], tmax16[16];
  __shared__ int needF[16], mixF[16];
  __shared__ int tlist[16], tmix[16], ntile;

  const int tid = threadIdx.x;
  const int l = tid & 63, w = tid >> 6;              // 4 waves
  const int lq = l & 31, hi = l >> 5;
  const int qb = blockIdx.x * 128;
  const int h = blockIdx.y, bt = blockIdx.z;
  const size_t hb = ((size_t)(bt * NHEADS + h)) * SEQ_N * HDIM;

  for (int i = tid; i < SEQ_N; i += 256) sid[i] = ids[i];
  __syncthreads();

  // --- tile classification: per-tile id-range, then per-qblock overlap ---
  {
    const int t = tid >> 4, j = tid & 15;
    int mn = 0x7fffffff, mx = 0x80000000;
#pragma unroll
    for (int s = 0; s < 4; ++s) {
      int v = sid[t * 64 + j * 4 + s];
      mn = min(mn, v); mx = max(mx, v);
    }
    mn = min(mn, __shfl_xor(mn, 1, 64)); mx = max(mx, __shfl_xor(mx, 1, 64));
    mn = min(mn, __shfl_xor(mn, 2, 64)); mx = max(mx, __shfl_xor(mx, 2, 64));
    mn = min(mn, __shfl_xor(mn, 4, 64)); mx = max(mx, __shfl_xor(mx, 4, 64));
    mn = min(mn, __shfl_xor(mn, 8, 64)); mx = max(mx, __shfl_xor(mx, 8, 64));
    if (j == 0) { tmin16[t] = mn; tmax16[t] = mx; }
  }
  __syncthreads();
  {
    const int t = tid >> 4, j = tid & 15;
    int any, all;
    if (tmin16[t] == tmax16[t]) {                    // tile has uniform id
      const int tval = tmin16[t];
      any = 0; all = 1;
#pragma unroll
      for (int r = 0; r < 8; ++r) {
        const int qr = qb + j * 8 + r;
        const int a = (qr < NLAT) ? 1 : (sid[qr] == tval);
        any |= a; all &= a;
      }
    } else { any = 1; all = 0; }                     // conservative fallback
    any |= __shfl_xor(any, 1, 64); all &= __shfl_xor(all, 1, 64);
    any |= __shfl_xor(any, 2, 64); all &= __shfl_xor(all, 2, 64);
    any |= __shfl_xor(any, 4, 64); all &= __shfl_xor(all, 4, 64);
    any |= __shfl_xor(any, 8, 64); all &= __shfl_xor(all, 8, 64);
    if (j == 0) { needF[t] = any; mixF[t] = !all; }
  }
  __syncthreads();
  if (tid == 0) {
    int n = 0;
    for (int t = 0; t < 16; ++t)
      if (needF[t]) { tlist[n] = t; tmix[n] = mixF[t]; ++n; }
    ntile = n;
  }
  __syncthreads();
  const int nt = ntile;

  // per-lane q info: wave w owns q rows qb + 32w .. +32; lane owns ONE q column
  const int q = qb + w * 32 + lq;
  const int qid = sid[q];
  const bool lat = (q < NLAT);

  // Q fragments: lane needs Q[q][kk*16 + hi*8 .. +8], kk = 0..3 (16 VGPR total)
  bf16x8 qf[4];
#pragma unroll
  for (int kk = 0; kk < 4; ++kk)
    qf[kk] = *(const bf16x8*)(qg + hb + (size_t)q * HDIM + kk * 16 + hi * 8);

  f32x16 o0, o1;
#pragma unroll
  for (int r = 0; r < 16; ++r) { o0[r] = 0.f; o1[r] = 0.f; }
  float mrun = -1e30f, lrun = 0.f;

  auto stage = [&](int buf, int t) {
    const int kb = t * 64;
#pragma unroll
    for (int i = 0; i < 2; ++i) {
      const int ch = tid + 256 * i;                  // 0..511 16B chunks
      const int r = ch >> 3, c = ch & 7;
      const int cs = (c ^ (r & 7)) * 8;              // pre-swizzled source (rule 21)
      GLOAD_LDS16(kg + hb + (size_t)(kb + r) * HDIM + cs, &sK[buf][ch * 8]);
      GLOAD_LDS16(vtg + hb + (size_t)r * SEQ_N + kb + cs, &sVT[buf][ch * 8]);
    }
  };

  if (nt > 0) stage(0, tlist[0]);
  __syncthreads();

  for (int i = 0; i < nt; ++i) {
    const int b = i & 1;
    if (i + 1 < nt) stage(b ^ 1, tlist[i + 1]);
    const int kb = tlist[i] * 64;

    // QK^T: p = P[s][q] (s in 2 blocks of 32; lane col = its q)
    f32x16 p0, p1;
#pragma unroll
    for (int r = 0; r < 16; ++r) { p0[r] = 0.f; p1[r] = 0.f; }
#pragma unroll
    for (int kk = 0; kk < 4; ++kk) {
      const int cc = ((2 * kk + hi) ^ (lq & 7)) * 8;
      const bf16x8 kf0 = *(const bf16x8*)&sK[b][lq * 64 + cc];
      p0 = MFMA32(kf0, qf[kk], p0);
      const bf16x8 kf1 = *(const bf16x8*)&sK[b][(32 + lq) * 64 + cc];
      p1 = MFMA32(kf1, qf[kk], p1);
    }

    // mask (mixed tiles only): s_local = (r&3) + 8*(r>>2) + 4*hi
    if (tmix[i] && !lat) {
#pragma unroll
      for (int qd = 0; qd < 4; ++qd) {
        const int4v s4a = *(const int4v*)&sid[kb + 8 * qd + 4 * hi];
        const int4v s4b = *(const int4v*)&sid[kb + 32 + 8 * qd + 4 * hi];
#pragma unroll
        for (int t2 = 0; t2 < 4; ++t2) {
          if (s4a[t2] != qid) p0[4 * qd + t2] = -1e30f;
          if (s4b[t2] != qid) p1[4 * qd + t2] = -1e30f;
        }
      }
    }

    // in-lane softmax over the tile's 64 s (32 regs + paired lane)
    float mx = p0[0];
#pragma unroll
    for (int r = 1; r < 16; ++r) mx = fmaxf(mx, p0[r]);
#pragma unroll
    for (int r = 0; r < 16; ++r) mx = fmaxf(mx, p1[r]);
    {
      int a = __float_as_int(mx), bsw = a;
      plswap(a, bsw);
      mx = fmaxf(__int_as_float(a), __int_as_float(bsw));
    }
    const float mn = fmaxf(mrun, mx);
    const float ros = exp2f(mrun - mn);
    mrun = mn;
    float tsum = 0.f;
#pragma unroll
    for (int r = 0; r < 16; ++r) { p0[r] = exp2f(p0[r] - mn); tsum += p0[r]; }
#pragma unroll
    for (int r = 0; r < 16; ++r) { p1[r] = exp2f(p1[r] - mn); tsum += p1[r]; }
    {
      int a = __float_as_int(tsum), bsw = a;
      plswap(a, bsw);
      tsum = __int_as_float(a) + __int_as_float(bsw);
    }
    lrun = lrun * ros + tsum;
#pragma unroll
    for (int r = 0; r < 16; ++r) { o0[r] *= ros; o1[r] *= ros; }

    // P -> bf16 PV A-fragments (T12: 4 cvt_pk + 2 permlane per kk) + PV MFMA
#pragma unroll
    for (int kk = 0; kk < 4; ++kk) {
      const f32x16& pp = (kk < 2) ? p0 : p1;
      const int c0 = 2 * (kk & 1);                   // reg-quad base
      int xa, xb, ya, yb;
      asm("v_cvt_pk_bf16_f32 %0, %1, %2" : "=v"(xa) : "v"(pp[4*c0+0]), "v"(pp[4*c0+1]));
      asm("v_cvt_pk_bf16_f32 %0, %1, %2" : "=v"(xb) : "v"(pp[4*c0+2]), "v"(pp[4*c0+3]));
      asm("v_cvt_pk_bf16_f32 %0, %1, %2" : "=v"(ya) : "v"(pp[4*c0+4]), "v"(pp[4*c0+5]));
      asm("v_cvt_pk_bf16_f32 %0, %1, %2" : "=v"(yb) : "v"(pp[4*c0+6]), "v"(pp[4*c0+7]));
      plswap(xa, ya);
      plswap(xb, yb);
      union { int4v iv; bf16x8 hv; } u;
      u.iv = (int4v){xa, xb, ya, yb};                // P[s=kk*16+hi*8 .. +8][q]

      const int cc = ((2 * kk + hi) ^ (lq & 7)) * 8;
      const bf16x8 v0 = *(const bf16x8*)&sVT[b][lq * 64 + cc];
      o0 = MFMA32(v0, u.hv, o0);                     // D[d=lq-block0][q]
      const bf16x8 v1 = *(const bf16x8*)&sVT[b][(32 + lq) * 64 + cc];
      o1 = MFMA32(v1, u.hv, o1);                     // D[d=32+..][q]
    }
    __syncthreads();   // one barrier/tile: drains stage vmcnt, protects buffers
  }

  // epilogue: O[d][q]/lrun -> ao[bt*S + q][h*64 + d], 8B vector stores
  const float inv = (lrun > 0.f) ? (1.f / lrun) : 0.f;
  short* aor = ao + ((size_t)(bt * SEQ_N + q)) * DMODEL + h * HDIM;
#pragma unroll
  for (int qd = 0; qd < 4; ++qd) {
    short4v v0, v1;
#pragma unroll
    for (int t2 = 0; t2 < 4; ++t2) {
      v0[t2] = f2bf(o0[4 * qd + t2] * inv);
      v1[t2] = f2bf(o1[4 * qd + t2] * inv);
    }
    const int d0 = 8 * qd + 4 * hi;                  // d = (r&3)+8*(r>>2)+4*hi
    *(short4v*)(aor + d0) = v0;
    *(short4v*)(aor + 32 + d0) = v1;
  }
}

// ---------------------------------------------------------------------------
// Host launcher
// ---------------------------------------------------------------------------
extern "C" void kernel_launch(void* const* d_in, const int* in_sizes, int n_in,
                              void* d_out, int out_size, void* d_ws, size_t ws_size,
                              hipStream_t stream) {
  const float* x  = (const float*)d_in[0];
  const int* ids  = (const int*)d_in[1];
  const float* Wq = (const float*)d_in[2];
  const float* bq = (const float*)d_in[3];
  const float* Wk = (const float*)d_in[4];
  const float* bk = (const float*)d_in[5];
  const float* Wv = (const float*)d_in[6];
  const float* bv = (const float*)d_in[7];
  const float* Wo = (const float*)d_in[8];
  const float* bo = (const float*)d_in[9];
  float* out = (float*)d_out;

  short* ws     = (short*)d_ws;
  short* x_bf   = ws;                          // 8192*1024
  short* wqkv_t = x_bf + 8388608;              // 3072*1024 (B^T: [n][k])
  short* wo_t   = wqkv_t + 3145728;            // 1024*1024 (B^T: [o][k])
  short* q_bf   = wo_t + 1048576;              // [bt][h][s][d]
  short* k_bf   = q_bf + 8388608;              // [bt][h][s][d]
  short* vt_bf  = k_bf + 8388608;              // [bt][h][d][s]  (transposed)
  short* ao_bf  = vt_bf + 8388608;             // [bt*s][h*d]

  cvt_plain<<<8192, 256, 0, stream>>>(x, x_bf, 2097152);
  dim3 tg(16, 16);
  cvt_T<<<tg, 256, 0, stream>>>(Wq, wqkv_t);
  cvt_T<<<tg, 256, 0, stream>>>(Wk, wqkv_t + 1048576);
  cvt_T<<<tg, 256, 0, stream>>>(Wv, wqkv_t + 2097152);
  cvt_T<<<tg, 256, 0, stream>>>(Wo, wo_t);

  gemm_bf16<0><<<dim3(24, 64), 256, 0, stream>>>(x_bf, wqkv_t, bq, bk, bv,
                                                 q_bf, nullptr, nullptr);
  attn_kernel<<<dim3(8, NHEADS, BT_N), 256, 0, stream>>>(q_bf, k_bf, vt_bf, ids, ao_bf);
  gemm_bf16<1><<<dim3(8, 64), 256, 0, stream>>>(ao_bf, wo_t, nullptr, nullptr, nullptr,
                                                nullptr, bo, out);
}

// Round 7
// 279.316 us; speedup vs baseline: 1.5943x; 1.1513x over previous
//
#include <hip/hip_runtime.h>
#include <cstdint>
#include <cstddef>

// ---------------------------------------------------------------------------
// SpaceSelfAttentionModality on MI355X (gfx950)
// cvt(x) -> transpose-cvt(W) -> QKV GEMM (q,k row-major + V TRANSPOSED)
//   -> flash attn (swapped-QK^T 32x32 MFMA, in-register softmax, tile skip)
//   -> output-proj GEMM -> f32 out.
// R4->R5: GEMMs reverted to true m97 structure (single 32KB LDS buffer,
// 2-barrier K-loop, 4 blocks/CU) -- R1's explicit dbuf was the m132 trap
// (64KB LDS -> 2 blocks/CU -> ~440 TF).
// R5/R6: bench never ran (GPU acquisition / container failures) --
// identical resubmit to measure the R4 revert.
// ---------------------------------------------------------------------------

#define BT_N    8
#define SEQ_N   1024
#define DMODEL  1024
#define NHEADS  16
#define HDIM    64
#define NLAT    64

typedef __attribute__((ext_vector_type(4))) float f32x4;
typedef __attribute__((ext_vector_type(16))) float f32x16;
typedef __attribute__((ext_vector_type(8))) __bf16 bf16x8;
typedef __attribute__((ext_vector_type(4))) short short4v;
typedef __attribute__((ext_vector_type(8))) short short8v;
typedef __attribute__((ext_vector_type(4))) int int4v;
typedef __attribute__((ext_vector_type(2))) unsigned int uint2v;

__device__ __forceinline__ short f2bf(float f) {
  union { float f; unsigned u; } x; x.f = f;
  unsigned r = x.u + 0x7fffu + ((x.u >> 16) & 1u);   // RNE (no NaN inputs here)
  return (short)(r >> 16);
}

// swap hi-half of a with lo-half of b (lane pairs l <-> l^32)
__device__ __forceinline__ void plswap(int& a, int& b) {
#if __has_builtin(__builtin_amdgcn_permlane32_swap)
  uint2v r = __builtin_amdgcn_permlane32_swap((unsigned)a, (unsigned)b, false, false);
  a = (int)r.x; b = (int)r.y;
#else
  asm volatile("v_permlane32_swap_b32 %0, %1" : "+v"(a), "+v"(b));
#endif
}

#define GLOAD_LDS16(gsrc, ldst)                                                   \
  __builtin_amdgcn_global_load_lds(                                               \
      (const __attribute__((address_space(1))) void*)(gsrc),                      \
      (__attribute__((address_space(3))) void*)(ldst), 16, 0, 0)

#define MFMA16(a, b, c) __builtin_amdgcn_mfma_f32_16x16x32_bf16((a), (b), (c), 0, 0, 0)
#define MFMA32(a, b, c) __builtin_amdgcn_mfma_f32_32x32x16_bf16((a), (b), (c), 0, 0, 0)

// 1/sqrt(64) * log2(e): scores come out in log2 domain -> softmax uses exp2
#define QSCALE 0.18033688011112f

// ---------------------------------------------------------------------------
// Kernel 1: plain f32 -> bf16 convert
// ---------------------------------------------------------------------------
__global__ __launch_bounds__(256)
void cvt_plain(const float* __restrict__ in, short* __restrict__ out, int n4) {
  int i = blockIdx.x * 256 + threadIdx.x;
  if (i >= n4) return;
  float4 f = reinterpret_cast<const float4*>(in)[i];
  short4v o;
  o.x = f2bf(f.x); o.y = f2bf(f.y); o.z = f2bf(f.z); o.w = f2bf(f.w);
  reinterpret_cast<short4v*>(out)[i] = o;
}

// ---------------------------------------------------------------------------
// Kernel 2: 1024x1024 f32 -> transposed bf16 (out[c][r] = in[r][c])
// ---------------------------------------------------------------------------
__global__ __launch_bounds__(256)
void cvt_T(const float* __restrict__ in, short* __restrict__ out) {
  __shared__ short t[64][65];
  int tc = blockIdx.x * 64, tr = blockIdx.y * 64;
  int lx = threadIdx.x & 63, ly = threadIdx.x >> 6;
#pragma unroll
  for (int i = 0; i < 16; ++i) {
    int r = ly + i * 4;
    t[r][lx] = f2bf(in[(size_t)(tr + r) * 1024 + tc + lx]);
  }
  __syncthreads();
#pragma unroll
  for (int i = 0; i < 16; ++i) {
    int c = ly + i * 4;
    out[(size_t)(tc + c) * 1024 + tr + lx] = t[lx][c];
  }
}

// ---------------------------------------------------------------------------
// Kernel 3/5: bf16 GEMM, C = A[M x 1024] * Bt[N x 1024]^T.  m97 structure:
// 128x128 tile, BK=64, SINGLE 32KB LDS buffer, 2-barrier K-loop,
// global_load_lds width-16 staging, 16x16x32 MFMA, 4x4 frags/wave.
// MODE 0: QKV epilogue (bias, q log2e-scale; q,k -> [bt][h][s][d]; v -> [bt][h][d][s]).
// MODE 1: proj epilogue (add bo, f32 row-major out).
// ---------------------------------------------------------------------------
template <int MODE>
__global__ __launch_bounds__(256, 4)
void gemm_bf16(const short* __restrict__ A, const short* __restrict__ Bt,
               const float* __restrict__ bq, const float* __restrict__ bk,
               const float* __restrict__ bv, short* __restrict__ qkv_out,
               const float* __restrict__ bo, float* __restrict__ out) {
  __shared__ __align__(16) short sA[128 * 64];
  __shared__ __align__(16) short sB[128 * 64];
  const int tid = threadIdx.x;
  const int l = tid & 63, w = tid >> 6;
  const int wr = w >> 1, wc = w & 1;
  const int lg = l >> 4, li = l & 15;
  const int m0 = blockIdx.y * 128, n0 = blockIdx.x * 128;

  f32x4 acc[4][4] = {};

  const int NK = 1024 / 64;
  for (int kt = 0; kt < NK; ++kt) {
    const int kb = kt * 64;
    // stage: 256 threads x 4 chunks of 16B per array
#pragma unroll
    for (int i = 0; i < 4; ++i) {
      int ch = tid + 256 * i;        // 0..1023, 16B chunks
      int r = ch >> 3, c = ch & 7;
      GLOAD_LDS16(A + (size_t)(m0 + r) * 1024 + kb + c * 8, &sA[ch * 8]);
    }
#pragma unroll
    for (int i = 0; i < 4; ++i) {
      int ch = tid + 256 * i;
      int r = ch >> 3, c = ch & 7;
      GLOAD_LDS16(Bt + (size_t)(n0 + r) * 1024 + kb + c * 8, &sB[ch * 8]);
    }
    __syncthreads();                  // drains vmcnt (gload_lds) before reads
#pragma unroll
    for (int kk = 0; kk < 64; kk += 32) {
      bf16x8 af[4], bfr[4];
#pragma unroll
      for (int mi = 0; mi < 4; ++mi)
        af[mi] = *(const bf16x8*)&sA[(wr * 64 + mi * 16 + li) * 64 + kk + lg * 8];
#pragma unroll
      for (int ni = 0; ni < 4; ++ni)
        bfr[ni] = *(const bf16x8*)&sB[(wc * 64 + ni * 16 + li) * 64 + kk + lg * 8];
#pragma unroll
      for (int mi = 0; mi < 4; ++mi)
#pragma unroll
        for (int ni = 0; ni < 4; ++ni)
          acc[mi][ni] = MFMA16(af[mi], bfr[ni], acc[mi][ni]);
    }
    __syncthreads();                  // protect buffer before next stage
  }

  if (MODE == 0) {
#pragma unroll
    for (int ni = 0; ni < 4; ++ni) {
      const int n = n0 + wc * 64 + ni * 16 + li;
      const int which = n >> 10;                  // 0=q 1=k 2=v
      const int hd_idx = n & 1023;
      const float* bias = (which == 0) ? bq : ((which == 1) ? bk : bv);
      const float bval = bias[hd_idx];
      const int h = hd_idx >> 6, d = hd_idx & 63;
      short* dst = qkv_out + (size_t)which * (BT_N * NHEADS * SEQ_N * HDIM);
#pragma unroll
      for (int mi = 0; mi < 4; ++mi) {
        const int mbase = m0 + wr * 64 + mi * 16 + lg * 4;
        const int bt = mbase >> 10, s0 = mbase & 1023;
        if (which == 2) {
          short4v pv;
#pragma unroll
          for (int reg = 0; reg < 4; ++reg) pv[reg] = f2bf(acc[mi][ni][reg] + bval);
          *(short4v*)(dst + (((size_t)(bt * NHEADS + h)) * HDIM + d) * SEQ_N + s0) = pv;
        } else {
#pragma unroll
          for (int reg = 0; reg < 4; ++reg) {
            float v = acc[mi][ni][reg] + bval;
            if (which == 0) v *= QSCALE;
            dst[(((size_t)(bt * NHEADS + h)) * SEQ_N + s0 + reg) * HDIM + d] = f2bf(v);
          }
        }
      }
    }
  } else {
#pragma unroll
    for (int ni = 0; ni < 4; ++ni) {
      const int n = n0 + wc * 64 + ni * 16 + li;
      const float bval = bo[n];
#pragma unroll
      for (int mi = 0; mi < 4; ++mi) {
#pragma unroll
        for (int reg = 0; reg < 4; ++reg) {
          const int m = m0 + wr * 64 + mi * 16 + lg * 4 + reg;
          out[(size_t)m * 1024 + n] = acc[mi][ni][reg] + bval;
        }
      }
    }
  }
}

// ---------------------------------------------------------------------------
// Kernel 4: flash attention, swapped-QK^T structure (m214/§B port):
//   4 waves x 32 q-rows = 128 q/block; KVBLK=64; mfma_32x32x16.
//   QK^T computed as mfma(A=K, B=Q) -> D = P[s][q]: lane owns one q column,
//   softmax is IN-LANE (31 fmax + permlane32_swap pair-combine, no shfl/LDS).
//   P -> bf16 PV A-fragments via cvt_pk_bf16 + permlane32_swap (T12).
//   O accumulates as D[d][q]; per-lane scalar rescale; exp2 domain.
// ---------------------------------------------------------------------------
__global__ __launch_bounds__(256, 4)
void attn_kernel(const short* __restrict__ qg, const short* __restrict__ kg,
                 const short* __restrict__ vtg, const int* __restrict__ ids,
                 short* __restrict__ ao) {
  __shared__ __align__(16) short sK[2][64 * 64];    // K tile [s][d], chunk-swizzled
  __shared__ __align__(16) short sVT[2][64 * 64];   // V^T tile [d][s], chunk-swizzled
  __shared__ int sid[SEQ_N];
  __shared__ int tmin16[16], tmax16[16];
  __shared__ int needF[16], mixF[16];
  __shared__ int tlist[16], tmix[16], ntile;

  const int tid = threadIdx.x;
  const int l = tid & 63, w = tid >> 6;              // 4 waves
  const int lq = l & 31, hi = l >> 5;
  const int qb = blockIdx.x * 128;
  const int h = blockIdx.y, bt = blockIdx.z;
  const size_t hb = ((size_t)(bt * NHEADS + h)) * SEQ_N * HDIM;

  for (int i = tid; i < SEQ_N; i += 256) sid[i] = ids[i];
  __syncthreads();

  // --- tile classification: per-tile id-range, then per-qblock overlap ---
  {
    const int t = tid >> 4, j = tid & 15;
    int mn = 0x7fffffff, mx = 0x80000000;
#pragma unroll
    for (int s = 0; s < 4; ++s) {
      int v = sid[t * 64 + j * 4 + s];
      mn = min(mn, v); mx = max(mx, v);
    }
    mn = min(mn, __shfl_xor(mn, 1, 64)); mx = max(mx, __shfl_xor(mx, 1, 64));
    mn = min(mn, __shfl_xor(mn, 2, 64)); mx = max(mx, __shfl_xor(mx, 2, 64));
    mn = min(mn, __shfl_xor(mn, 4, 64)); mx = max(mx, __shfl_xor(mx, 4, 64));
    mn = min(mn, __shfl_xor(mn, 8, 64)); mx = max(mx, __shfl_xor(mx, 8, 64));
    if (j == 0) { tmin16[t] = mn; tmax16[t] = mx; }
  }
  __syncthreads();
  {
    const int t = tid >> 4, j = tid & 15;
    int any, all;
    if (tmin16[t] == tmax16[t]) {                    // tile has uniform id
      const int tval = tmin16[t];
      any = 0; all = 1;
#pragma unroll
      for (int r = 0; r < 8; ++r) {
        const int qr = qb + j * 8 + r;
        const int a = (qr < NLAT) ? 1 : (sid[qr] == tval);
        any |= a; all &= a;
      }
    } else { any = 1; all = 0; }                     // conservative fallback
    any |= __shfl_xor(any, 1, 64); all &= __shfl_xor(all, 1, 64);
    any |= __shfl_xor(any, 2, 64); all &= __shfl_xor(all, 2, 64);
    any |= __shfl_xor(any, 4, 64); all &= __shfl_xor(all, 4, 64);
    any |= __shfl_xor(any, 8, 64); all &= __shfl_xor(all, 8, 64);
    if (j == 0) { needF[t] = any; mixF[t] = !all; }
  }
  __syncthreads();
  if (tid == 0) {
    int n = 0;
    for (int t = 0; t < 16; ++t)
      if (needF[t]) { tlist[n] = t; tmix[n] = mixF[t]; ++n; }
    ntile = n;
  }
  __syncthreads();
  const int nt = ntile;

  // per-lane q info: wave w owns q rows qb + 32w .. +32; lane owns ONE q column
  const int q = qb + w * 32 + lq;
  const int qid = sid[q];
  const bool lat = (q < NLAT);

  // Q fragments: lane needs Q[q][kk*16 + hi*8 .. +8], kk = 0..3 (16 VGPR total)
  bf16x8 qf[4];
#pragma unroll
  for (int kk = 0; kk < 4; ++kk)
    qf[kk] = *(const bf16x8*)(qg + hb + (size_t)q * HDIM + kk * 16 + hi * 8);

  f32x16 o0, o1;
#pragma unroll
  for (int r = 0; r < 16; ++r) { o0[r] = 0.f; o1[r] = 0.f; }
  float mrun = -1e30f, lrun = 0.f;

  auto stage = [&](int buf, int t) {
    const int kb = t * 64;
#pragma unroll
    for (int i = 0; i < 2; ++i) {
      const int ch = tid + 256 * i;                  // 0..511 16B chunks
      const int r = ch >> 3, c = ch & 7;
      const int cs = (c ^ (r & 7)) * 8;              // pre-swizzled source (rule 21)
      GLOAD_LDS16(kg + hb + (size_t)(kb + r) * HDIM + cs, &sK[buf][ch * 8]);
      GLOAD_LDS16(vtg + hb + (size_t)r * SEQ_N + kb + cs, &sVT[buf][ch * 8]);
    }
  };

  if (nt > 0) stage(0, tlist[0]);
  __syncthreads();

  for (int i = 0; i < nt; ++i) {
    const int b = i & 1;
    if (i + 1 < nt) stage(b ^ 1, tlist[i + 1]);
    const int kb = tlist[i] * 64;

    // QK^T: p = P[s][q] (s in 2 blocks of 32; lane col = its q)
    f32x16 p0, p1;
#pragma unroll
    for (int r = 0; r < 16; ++r) { p0[r] = 0.f; p1[r] = 0.f; }
#pragma unroll
    for (int kk = 0; kk < 4; ++kk) {
      const int cc = ((2 * kk + hi) ^ (lq & 7)) * 8;
      const bf16x8 kf0 = *(const bf16x8*)&sK[b][lq * 64 + cc];
      p0 = MFMA32(kf0, qf[kk], p0);
      const bf16x8 kf1 = *(const bf16x8*)&sK[b][(32 + lq) * 64 + cc];
      p1 = MFMA32(kf1, qf[kk], p1);
    }

    // mask (mixed tiles only): s_local = (r&3) + 8*(r>>2) + 4*hi
    if (tmix[i] && !lat) {
#pragma unroll
      for (int qd = 0; qd < 4; ++qd) {
        const int4v s4a = *(const int4v*)&sid[kb + 8 * qd + 4 * hi];
        const int4v s4b = *(const int4v*)&sid[kb + 32 + 8 * qd + 4 * hi];
#pragma unroll
        for (int t2 = 0; t2 < 4; ++t2) {
          if (s4a[t2] != qid) p0[4 * qd + t2] = -1e30f;
          if (s4b[t2] != qid) p1[4 * qd + t2] = -1e30f;
        }
      }
    }

    // in-lane softmax over the tile's 64 s (32 regs + paired lane)
    float mx = p0[0];
#pragma unroll
    for (int r = 1; r < 16; ++r) mx = fmaxf(mx, p0[r]);
#pragma unroll
    for (int r = 0; r < 16; ++r) mx = fmaxf(mx, p1[r]);
    {
      int a = __float_as_int(mx), bsw = a;
      plswap(a, bsw);
      mx = fmaxf(__int_as_float(a), __int_as_float(bsw));
    }
    const float mn = fmaxf(mrun, mx);
    const float ros = exp2f(mrun - mn);
    mrun = mn;
    float tsum = 0.f;
#pragma unroll
    for (int r = 0; r < 16; ++r) { p0[r] = exp2f(p0[r] - mn); tsum += p0[r]; }
#pragma unroll
    for (int r = 0; r < 16; ++r) { p1[r] = exp2f(p1[r] - mn); tsum += p1[r]; }
    {
      int a = __float_as_int(tsum), bsw = a;
      plswap(a, bsw);
      tsum = __int_as_float(a) + __int_as_float(bsw);
    }
    lrun = lrun * ros + tsum;
#pragma unroll
    for (int r = 0; r < 16; ++r) { o0[r] *= ros; o1[r] *= ros; }

    // P -> bf16 PV A-fragments (T12: 4 cvt_pk + 2 permlane per kk) + PV MFMA
#pragma unroll
    for (int kk = 0; kk < 4; ++kk) {
      const f32x16& pp = (kk < 2) ? p0 : p1;
      const int c0 = 2 * (kk & 1);                   // reg-quad base
      int xa, xb, ya, yb;
      asm("v_cvt_pk_bf16_f32 %0, %1, %2" : "=v"(xa) : "v"(pp[4*c0+0]), "v"(pp[4*c0+1]));
      asm("v_cvt_pk_bf16_f32 %0, %1, %2" : "=v"(xb) : "v"(pp[4*c0+2]), "v"(pp[4*c0+3]));
      asm("v_cvt_pk_bf16_f32 %0, %1, %2" : "=v"(ya) : "v"(pp[4*c0+4]), "v"(pp[4*c0+5]));
      asm("v_cvt_pk_bf16_f32 %0, %1, %2" : "=v"(yb) : "v"(pp[4*c0+6]), "v"(pp[4*c0+7]));
      plswap(xa, ya);
      plswap(xb, yb);
      union { int4v iv; bf16x8 hv; } u;
      u.iv = (int4v){xa, xb, ya, yb};                // P[s=kk*16+hi*8 .. +8][q]

      const int cc = ((2 * kk + hi) ^ (lq & 7)) * 8;
      const bf16x8 v0 = *(const bf16x8*)&sVT[b][lq * 64 + cc];
      o0 = MFMA32(v0, u.hv, o0);                     // D[d=lq-block0][q]
      const bf16x8 v1 = *(const bf16x8*)&sVT[b][(32 + lq) * 64 + cc];
      o1 = MFMA32(v1, u.hv, o1);                     // D[d=32+..][q]
    }
    __syncthreads();   // one barrier/tile: drains stage vmcnt, protects buffers
  }

  // epilogue: O[d][q]/lrun -> ao[bt*S + q][h*64 + d], 8B vector stores
  const float inv = (lrun > 0.f) ? (1.f / lrun) : 0.f;
  short* aor = ao + ((size_t)(bt * SEQ_N + q)) * DMODEL + h * HDIM;
#pragma unroll
  for (int qd = 0; qd < 4; ++qd) {
    short4v v0, v1;
#pragma unroll
    for (int t2 = 0; t2 < 4; ++t2) {
      v0[t2] = f2bf(o0[4 * qd + t2] * inv);
      v1[t2] = f2bf(o1[4 * qd + t2] * inv);
    }
    const int d0 = 8 * qd + 4 * hi;                  // d = (r&3)+8*(r>>2)+4*hi
    *(short4v*)(aor + d0) = v0;
    *(short4v*)(aor + 32 + d0) = v1;
  }
}

// ---------------------------------------------------------------------------
// Host launcher
// ---------------------------------------------------------------------------
extern "C" void kernel_launch(void* const* d_in, const int* in_sizes, int n_in,
                              void* d_out, int out_size, void* d_ws, size_t ws_size,
                              hipStream_t stream) {
  const float* x  = (const float*)d_in[0];
  const int* ids  = (const int*)d_in[1];
  const float* Wq = (const float*)d_in[2];
  const float* bq = (const float*)d_in[3];
  const float* Wk = (const float*)d_in[4];
  const float* bk = (const float*)d_in[5];
  const float* Wv = (const float*)d_in[6];
  const float* bv = (const float*)d_in[7];
  const float* Wo = (const float*)d_in[8];
  const float* bo = (const float*)d_in[9];
  float* out = (float*)d_out;

  short* ws     = (short*)d_ws;
  short* x_bf   = ws;                          // 8192*1024
  short* wqkv_t = x_bf + 8388608;              // 3072*1024 (B^T: [n][k])
  short* wo_t   = wqkv_t + 3145728;            // 1024*1024 (B^T: [o][k])
  short* q_bf   = wo_t + 1048576;              // [bt][h][s][d]
  short* k_bf   = q_bf + 8388608;              // [bt][h][s][d]
  short* vt_bf  = k_bf + 8388608;              // [bt][h][d][s]  (transposed)
  short* ao_bf  = vt_bf + 8388608;             // [bt*s][h*d]

  cvt_plain<<<8192, 256, 0, stream>>>(x, x_bf, 2097152);
  dim3 tg(16, 16);
  cvt_T<<<tg, 256, 0, stream>>>(Wq, wqkv_t);
  cvt_T<<<tg, 256, 0, stream>>>(Wk, wqkv_t + 1048576);
  cvt_T<<<tg, 256, 0, stream>>>(Wv, wqkv_t + 2097152);
  cvt_T<<<tg, 256, 0, stream>>>(Wo, wo_t);

  gemm_bf16<0><<<dim3(24, 64), 256, 0, stream>>>(x_bf, wqkv_t, bq, bk, bv,
                                                 q_bf, nullptr, nullptr);
  attn_kernel<<<dim3(8, NHEADS, BT_N), 256, 0, stream>>>(q_bf, k_bf, vt_bf, ids, ao_bf);
  gemm_bf16<1><<<dim3(8, 64), 256, 0, stream>>>(ao_bf, wo_t, nullptr, nullptr, nullptr,
                                                nullptr, bo, out);
}